// Round 5
// baseline (26.286 us; speedup 1.0000x reference)
//
#include <hip/hip_runtime.h>

// CrossNet (DCN cross layers): B=16384, D=1024, L=3
//
// R4: 4 rows per wave + R3 algebra (alpha-scalar form needs no xl state):
//   d_t = x0 . w_t (3 dots/row, all independent)
//   c1 = b0.w1, c2 = (b0+b1).w2, bs = b0+b1+b2  (row-independent)
//   alpha: a1 = 1+d0; a2 = a1 + (a1*d1 + c1); a3 = a2 + (a2*d2 + c2)
//   out = a3 * x0 + bs
// w/b fragments (24 KB) loaded once per wave and amortized over 4 rows:
// per-row VMEM instrs 20 -> 14, aggregate w/b re-read traffic halves.

#define CN_B 16384
#define CN_D 1024
#define ROWS_PER_WAVE 4
#define WAVES_PER_BLOCK 4
#define ROWS_PER_BLOCK (ROWS_PER_WAVE * WAVES_PER_BLOCK)

__device__ __forceinline__ float dot4(const float4 a, const float4 b) {
  return a.x * b.x + a.y * b.y + a.z * b.z + a.w * b.w;
}

__global__ __launch_bounds__(256, 3) void crossnet_kernel(
    const float* __restrict__ x,
    const float* __restrict__ w,
    const float* __restrict__ bias,
    float* __restrict__ out) {
  const int tid  = threadIdx.x;
  const int wave = tid >> 6;
  const int lane = tid & 63;
  const int row0 = (blockIdx.x * WAVES_PER_BLOCK + wave) * ROWS_PER_WAVE;

  const float4* w0r = reinterpret_cast<const float4*>(w);
  const float4* w1r = reinterpret_cast<const float4*>(w + CN_D);
  const float4* w2r = reinterpret_cast<const float4*>(w + 2 * CN_D);
  const float4* b0r = reinterpret_cast<const float4*>(bias);
  const float4* b1r = reinterpret_cast<const float4*>(bias + CN_D);
  const float4* b2r = reinterpret_cast<const float4*>(bias + 2 * CN_D);

  // x0 for 4 rows: issue the HBM loads first (longest latency)
  float4 x0[ROWS_PER_WAVE][4];
  #pragma unroll
  for (int r = 0; r < ROWS_PER_WAVE; ++r) {
    const float4* xr = reinterpret_cast<const float4*>(x + (size_t)(row0 + r) * CN_D);
    #pragma unroll
    for (int k = 0; k < 4; ++k) x0[r][k] = xr[k * 64 + lane];
  }

  // partial dots: d[r][t], plus row-independent c1, c2, bs
  float d[ROWS_PER_WAVE][3];
  #pragma unroll
  for (int r = 0; r < ROWS_PER_WAVE; ++r) d[r][0] = d[r][1] = d[r][2] = 0.f;
  float c1 = 0.f, c2 = 0.f;
  float4 bs[4];

  #pragma unroll
  for (int k = 0; k < 4; ++k) {
    const int idx = k * 64 + lane;
    const float4 w0 = w0r[idx];
    const float4 w1 = w1r[idx];
    const float4 w2 = w2r[idx];
    const float4 b0 = b0r[idx];
    const float4 b1 = b1r[idx];
    const float4 b2 = b2r[idx];

    #pragma unroll
    for (int r = 0; r < ROWS_PER_WAVE; ++r) {
      d[r][0] += dot4(x0[r][k], w0);
      d[r][1] += dot4(x0[r][k], w1);
      d[r][2] += dot4(x0[r][k], w2);
    }

    c1 += dot4(b0, w1);
    float4 b01;
    b01.x = b0.x + b1.x; b01.y = b0.y + b1.y;
    b01.z = b0.z + b1.z; b01.w = b0.w + b1.w;
    c2 += dot4(b01, w2);
    bs[k].x = b01.x + b2.x; bs[k].y = b01.y + b2.y;
    bs[k].z = b01.z + b2.z; bs[k].w = b01.w + b2.w;
  }

  // one interleaved 64-lane butterfly over all 14 values
  #pragma unroll
  for (int off = 32; off > 0; off >>= 1) {
    #pragma unroll
    for (int r = 0; r < ROWS_PER_WAVE; ++r) {
      d[r][0] += __shfl_xor(d[r][0], off, 64);
      d[r][1] += __shfl_xor(d[r][1], off, 64);
      d[r][2] += __shfl_xor(d[r][2], off, 64);
    }
    c1 += __shfl_xor(c1, off, 64);
    c2 += __shfl_xor(c2, off, 64);
  }

  // scalar recurrence + store per row
  #pragma unroll
  for (int r = 0; r < ROWS_PER_WAVE; ++r) {
    float a = 1.0f + d[r][0];
    a = a + (a * d[r][1] + c1);
    a = a + (a * d[r][2] + c2);
    float4* orow = reinterpret_cast<float4*>(out + (size_t)(row0 + r) * CN_D);
    #pragma unroll
    for (int k = 0; k < 4; ++k) {
      float4 o;
      o.x = x0[r][k].x * a + bs[k].x;
      o.y = x0[r][k].y * a + bs[k].y;
      o.z = x0[r][k].z * a + bs[k].z;
      o.w = x0[r][k].w * a + bs[k].w;
      orow[k * 64 + lane] = o;
    }
  }
}

extern "C" void kernel_launch(void* const* d_in, const int* in_sizes, int n_in,
                              void* d_out, int out_size, void* d_ws, size_t ws_size,
                              hipStream_t stream) {
  const float* x    = (const float*)d_in[0];
  const float* w    = (const float*)d_in[1];
  const float* bias = (const float*)d_in[2];
  float* out        = (float*)d_out;

  crossnet_kernel<<<CN_B / ROWS_PER_BLOCK, 256, 0, stream>>>(x, w, bias, out);
}

// Round 6
// 24.610 us; speedup vs baseline: 1.0681x; 1.0681x over previous
//
#include <hip/hip_runtime.h>

// CrossNet (DCN cross layers): B=16384, D=1024, L=3
//   s_b     = sum_d xl[b,d] * w[l,d]
//   xl[b,d] = x0[b,d] * s_b + bias[l,d] + xl[b,d]
//
// R5: R2 structure (2 rows/wave, best measured: 25.5us) + NONTEMPORAL stores
// for the output stream. `out` is write-once data; streaming it past L2
// stops the write stream from evicting the x read stream in the 4MiB/XCD L2.
// 64 lanes x 16 floats/row, all state in registers, no LDS, no barriers.

#define CN_B 16384
#define CN_D 1024
#define CN_L 3
#define ROWS_PER_WAVE 2
#define WAVES_PER_BLOCK 4
#define ROWS_PER_BLOCK (ROWS_PER_WAVE * WAVES_PER_BLOCK)

__device__ __forceinline__ void nt_store_float4(float4* p, float4 v) {
  __builtin_nontemporal_store(v.x, &p->x);
  __builtin_nontemporal_store(v.y, &p->y);
  __builtin_nontemporal_store(v.z, &p->z);
  __builtin_nontemporal_store(v.w, &p->w);
}

__global__ __launch_bounds__(256, 4) void crossnet_kernel(
    const float* __restrict__ x,
    const float* __restrict__ w,
    const float* __restrict__ bias,
    float* __restrict__ out) {
  const int tid  = threadIdx.x;
  const int wave = tid >> 6;
  const int lane = tid & 63;
  const int row0 = (blockIdx.x * WAVES_PER_BLOCK + wave) * ROWS_PER_WAVE;

  const float4* xr0 = reinterpret_cast<const float4*>(x + (size_t)row0 * CN_D);
  const float4* xr1 = reinterpret_cast<const float4*>(x + (size_t)(row0 + 1) * CN_D);

  float4 x0a[4], xla[4], x0b[4], xlb[4];
  #pragma unroll
  for (int k = 0; k < 4; ++k) {
    x0a[k] = xr0[k * 64 + lane];
    x0b[k] = xr1[k * 64 + lane];
    xla[k] = x0a[k];
    xlb[k] = x0b[k];
  }

  #pragma unroll
  for (int l = 0; l < CN_L; ++l) {
    const float4* wrow = reinterpret_cast<const float4*>(w    + l * CN_D);
    const float4* brow = reinterpret_cast<const float4*>(bias + l * CN_D);
    float4 wl[4], bl[4];
    #pragma unroll
    for (int k = 0; k < 4; ++k) {
      wl[k] = wrow[k * 64 + lane];
      bl[k] = brow[k * 64 + lane];
    }

    // independent partial dots for the two rows
    float pa = 0.0f, pb = 0.0f;
    #pragma unroll
    for (int k = 0; k < 4; ++k) {
      pa += xla[k].x * wl[k].x; pb += xlb[k].x * wl[k].x;
      pa += xla[k].y * wl[k].y; pb += xlb[k].y * wl[k].y;
      pa += xla[k].z * wl[k].z; pb += xlb[k].z * wl[k].z;
      pa += xla[k].w * wl[k].w; pb += xlb[k].w * wl[k].w;
    }

    // two interleaved 64-lane butterflies (independent -> ILP=2)
    #pragma unroll
    for (int off = 32; off > 0; off >>= 1) {
      pa += __shfl_xor(pa, off, 64);
      pb += __shfl_xor(pb, off, 64);
    }

    #pragma unroll
    for (int k = 0; k < 4; ++k) {
      xla[k].x = x0a[k].x * pa + bl[k].x + xla[k].x;
      xla[k].y = x0a[k].y * pa + bl[k].y + xla[k].y;
      xla[k].z = x0a[k].z * pa + bl[k].z + xla[k].z;
      xla[k].w = x0a[k].w * pa + bl[k].w + xla[k].w;
      xlb[k].x = x0b[k].x * pb + bl[k].x + xlb[k].x;
      xlb[k].y = x0b[k].y * pb + bl[k].y + xlb[k].y;
      xlb[k].z = x0b[k].z * pb + bl[k].z + xlb[k].z;
      xlb[k].w = x0b[k].w * pb + bl[k].w + xlb[k].w;
    }
  }

  float4* or0 = reinterpret_cast<float4*>(out + (size_t)row0 * CN_D);
  float4* or1 = reinterpret_cast<float4*>(out + (size_t)(row0 + 1) * CN_D);
  #pragma unroll
  for (int k = 0; k < 4; ++k) {
    nt_store_float4(&or0[k * 64 + lane], xla[k]);
    nt_store_float4(&or1[k * 64 + lane], xlb[k]);
  }
}

extern "C" void kernel_launch(void* const* d_in, const int* in_sizes, int n_in,
                              void* d_out, int out_size, void* d_ws, size_t ws_size,
                              hipStream_t stream) {
  const float* x    = (const float*)d_in[0];
  const float* w    = (const float*)d_in[1];
  const float* bias = (const float*)d_in[2];
  float* out        = (float*)d_out;

  crossnet_kernel<<<CN_B / ROWS_PER_BLOCK, 256, 0, stream>>>(x, w, bias, out);
}